// Round 1
// baseline (19.351 us; speedup 1.0000x reference)
//
#include <hip/hip_runtime.h>
#include <hip/hip_bf16.h>

// Problem: B=512, N=64, D=128, 4 edge types.
// out[b] = softmax_j(select_k(leakyrelu((h*a_k) @ h^T), adj)) @ h

#define NB 512
#define NN 64
#define ND 128

typedef __bf16 bf16x8 __attribute__((ext_vector_type(8)));
typedef __bf16 bf16x4 __attribute__((ext_vector_type(4)));
typedef float  f32x4  __attribute__((ext_vector_type(4)));

#define HS 136   // h_lds row stride in bf16 elems (128 + 8 pad -> conflict-free ds_read_b128)
#define TS 72    // hT_lds row stride (64 + 8)
#define LS 68    // logits row stride in f32 (64 + 4)
#define AS 72    // alpha row stride in bf16 (64 + 8)

__global__ __launch_bounds__(256)
void gat_kernel(const float* __restrict__ hidden,
                const int*   __restrict__ adj,
                const float* __restrict__ a,
                float*       __restrict__ out)
{
    __shared__ __bf16 h_lds[NN * HS];    // 17408 B
    __shared__ __bf16 hT_lds[ND * TS];   // 18432 B
    __shared__ float  lg_lds[NN * LS];   // 17408 B
    __shared__ __bf16 al_lds[NN * AS];   //  9216 B
    __shared__ __bf16 a_lds[4 * 128];    //  1024 B   total ~63.5 KB -> 2 blocks/CU

    const int b    = blockIdx.x;
    const int t    = threadIdx.x;
    const int lane = t & 63;
    const int w    = t >> 6;            // wave id 0..3

    // ---- stage hidden[b] (f32 global) -> bf16 h_lds + transposed hT_lds ----
    const float4* hin = (const float4*)(hidden + (size_t)b * NN * ND);
    #pragma unroll
    for (int it = 0; it < 8; ++it) {
        int idx = it * 256 + t;          // 2048 float4 total
        int row = idx >> 5;              // 32 float4 per row
        int c4  = (idx & 31) << 2;       // d base
        float4 v = hin[idx];
        __bf16 b0 = (__bf16)v.x, b1 = (__bf16)v.y, b2 = (__bf16)v.z, b3 = (__bf16)v.w;
        bf16x4 pk = { b0, b1, b2, b3 };
        *(bf16x4*)&h_lds[row * HS + c4] = pk;   // 8B aligned store
        hT_lds[(c4 + 0) * TS + row] = b0;
        hT_lds[(c4 + 1) * TS + row] = b1;
        hT_lds[(c4 + 2) * TS + row] = b2;
        hT_lds[(c4 + 3) * TS + row] = b3;
    }
    a_lds[t]       = (__bf16)a[t];
    a_lds[t + 256] = (__bf16)a[t + 256];
    __syncthreads();

    // ---- e-GEMM: e_k = (h*a_k) @ h^T, per-wave row-tile w (rows w*16..w*16+15) ----
    const int g8 = (lane >> 4) * 8;      // k-group offset within K=32 slice
    bf16x8 hafrag[4][4];                 // [kk][k]
    {
        int i = w * 16 + (lane & 15);
        #pragma unroll
        for (int kk = 0; kk < 4; ++kk) {
            int d0 = kk * 32 + g8;
            bf16x8 hf = *(const bf16x8*)&h_lds[i * HS + d0];
            #pragma unroll
            for (int k = 0; k < 4; ++k) {
                bf16x8 af = *(const bf16x8*)&a_lds[k * 128 + d0];
                bf16x8 r;
                #pragma unroll
                for (int e = 0; e < 8; ++e)
                    r[e] = (__bf16)((float)hf[e] * (float)af[e]);
                hafrag[kk][k] = r;
            }
        }
    }

    const int* adjb = adj + (size_t)b * NN * NN;

    #pragma unroll
    for (int ct = 0; ct < 4; ++ct) {      // 4 col-tiles of 16 j's
        f32x4 acc[4] = {};                // one accumulator per edge type k
        int jr = ct * 16 + (lane & 15);
        #pragma unroll
        for (int kk = 0; kk < 4; ++kk) {
            bf16x8 bfr = *(const bf16x8*)&h_lds[jr * HS + kk * 32 + g8];
            #pragma unroll
            for (int k = 0; k < 4; ++k)
                acc[k] = __builtin_amdgcn_mfma_f32_16x16x32_bf16(hafrag[kk][k], bfr, acc[k], 0, 0, 0);
        }
        // fused leakyrelu + adj-select epilogue -> logits in LDS
        #pragma unroll
        for (int r = 0; r < 4; ++r) {
            int i = w * 16 + (lane >> 4) * 4 + r;     // C/D: row=(lane>>4)*4+reg
            int adjv = adjb[i * NN + jr];
            float e0 = fmaxf(acc[0][r], 0.2f * acc[0][r]);
            float e1 = fmaxf(acc[1][r], 0.2f * acc[1][r]);
            float e2 = fmaxf(acc[2][r], 0.2f * acc[2][r]);
            float e3 = fmaxf(acc[3][r], 0.2f * acc[3][r]);
            float lv = adjv == 1 ? e0 : adjv == 2 ? e1 : adjv == 3 ? e2 : adjv == 4 ? e3 : -9.0e15f;
            lg_lds[i * LS + jr] = lv;
        }
    }
    __syncthreads();

    // ---- wave-parallel softmax: 4 threads per row, 16 elems each ----
    {
        int row = t >> 2;
        int j0  = (t & 3) * 16;
        const float* lp = &lg_lds[row * LS + j0];
        float xv[16];
        *(float4*)&xv[0]  = *(const float4*)(lp + 0);
        *(float4*)&xv[4]  = *(const float4*)(lp + 4);
        *(float4*)&xv[8]  = *(const float4*)(lp + 8);
        *(float4*)&xv[12] = *(const float4*)(lp + 12);
        float m = xv[0];
        #pragma unroll
        for (int e = 1; e < 16; ++e) m = fmaxf(m, xv[e]);
        m = fmaxf(m, __shfl_xor(m, 1));
        m = fmaxf(m, __shfl_xor(m, 2));
        float s = 0.f;
        #pragma unroll
        for (int e = 0; e < 16; ++e) { float p = __expf(xv[e] - m); xv[e] = p; s += p; }
        s += __shfl_xor(s, 1);
        s += __shfl_xor(s, 2);
        float inv = 1.0f / s;
        __attribute__((aligned(16))) __bf16 ov[16];
        #pragma unroll
        for (int e = 0; e < 16; ++e) ov[e] = (__bf16)(xv[e] * inv);
        *(bf16x8*)&al_lds[row * AS + j0]     = *(bf16x8*)&ov[0];
        *(bf16x8*)&al_lds[row * AS + j0 + 8] = *(bf16x8*)&ov[8];
    }
    __syncthreads();

    // ---- PV: out = alpha @ h  (A = alpha bf16, B from transposed hT) ----
    {
        int i_a = w * 16 + (lane & 15);
        bf16x8 aA0 = *(const bf16x8*)&al_lds[i_a * AS + g8];        // K-slice 0 (j 0..31)
        bf16x8 aA1 = *(const bf16x8*)&al_lds[i_a * AS + 32 + g8];   // K-slice 1 (j 32..63)
        float* outb = out + (size_t)b * NN * ND;
        #pragma unroll
        for (int ct = 0; ct < 8; ++ct) {   // 8 col-tiles over D=128
            int dr = ct * 16 + (lane & 15);
            bf16x8 b0 = *(const bf16x8*)&hT_lds[dr * TS + g8];
            bf16x8 b1 = *(const bf16x8*)&hT_lds[dr * TS + 32 + g8];
            f32x4 acc = {};
            acc = __builtin_amdgcn_mfma_f32_16x16x32_bf16(aA0, b0, acc, 0, 0, 0);
            acc = __builtin_amdgcn_mfma_f32_16x16x32_bf16(aA1, b1, acc, 0, 0, 0);
            #pragma unroll
            for (int r = 0; r < 4; ++r) {
                int i = w * 16 + (lane >> 4) * 4 + r;
                outb[i * ND + dr] = acc[r];
            }
        }
    }
}

extern "C" void kernel_launch(void* const* d_in, const int* in_sizes, int n_in,
                              void* d_out, int out_size, void* d_ws, size_t ws_size,
                              hipStream_t stream) {
    const float* hidden = (const float*)d_in[0];
    const int*   adj    = (const int*)d_in[1];
    const float* a      = (const float*)d_in[2];
    float*       out    = (float*)d_out;
    gat_kernel<<<NB, 256, 0, stream>>>(hidden, adj, a, out);
}

// Round 3
// 16.619 us; speedup vs baseline: 1.1643x; 1.1643x over previous
//
#include <hip/hip_runtime.h>
#include <hip/hip_bf16.h>

// B=512, N=64, D=128, 4 edge types.
// out[b] = softmax_j(select_k(leakyrelu((h*a_k) @ h^T), adj)) @ h

#define NB 512
#define NN 64
#define ND 128
#define HS 136   // h_lds row stride (128 + 8 pad)
#define AS 72    // alpha row stride

typedef __bf16 bf16x8 __attribute__((ext_vector_type(8)));
typedef __bf16 bf16x4 __attribute__((ext_vector_type(4)));
typedef float  f32x4  __attribute__((ext_vector_type(4)));

__global__ __launch_bounds__(256)
void gat_kernel(const float* __restrict__ hidden,
                const int*   __restrict__ adj,
                const float* __restrict__ a,
                float*       __restrict__ out)
{
    __shared__ __bf16 h_lds[NN * HS];       // 17408 B  row-major, padded
    __shared__ __bf16 h_tr[8 * NN * 16];    // 16384 B  [dt][j][dcol] subtiled for tr-read
    __shared__ __bf16 al_lds[NN * AS];      //  9216 B  unnormalized exp(P)
    __shared__ float  a_lds[4 * ND];        //  2048 B  a in f32
                                            //  total 45056 B

    const int t = threadIdx.x;
    const int l = t & 63;
    const int w = t >> 6;
    const int b = blockIdx.x;
    const int g  = l >> 4;        // 16-lane group 0..3
    const int g8 = g << 3;
    const int i0 = w * 16 + (g << 2);   // C/D row base for this lane

    // ---- prefetch adj (consumed after e-GEMM; latency hides under staging) ----
    const int* adjb = adj + (size_t)b * NN * NN;
    int adjv[4][4];
    #pragma unroll
    for (int ct = 0; ct < 4; ++ct)
        #pragma unroll
        for (int r = 0; r < 4; ++r)
            adjv[ct][r] = adjb[(i0 + r) * NN + ct * 16 + (l & 15)];

    // ---- stage hidden[b]: f32 global -> bf16 h_lds (row-major) + h_tr (subtiled) ----
    // mapping: quad of lanes = 64B line; rows vary across lanes -> conflict-free b64 writes
    const float4* hin = (const float4*)(hidden + (size_t)b * NN * ND);
    #pragma unroll
    for (int it = 0; it < 8; ++it) {
        int row = ((l >> 2) & 15) | ((it >> 1) << 4);
        int f4  = (l & 3) | (w << 2) | ((it & 1) << 4);
        float4 v = hin[row * 32 + f4];
        bf16x4 pk = { (__bf16)v.x, (__bf16)v.y, (__bf16)v.z, (__bf16)v.w };
        int c4 = f4 << 2;
        *(bf16x4*)&h_lds[row * HS + c4] = pk;
        *(bf16x4*)&h_tr[((c4 >> 4) << 10) + (row << 4) + (c4 & 15)] = pk;
    }
    a_lds[t]       = a[t];
    a_lds[t + 256] = a[t + 256];
    __syncthreads();   // the only barrier

    // ---- e-GEMM: e_k = (h*a_k) @ h^T ; wave w owns rows w*16..w*16+15 ----
    const int irow = w * 16 + (l & 15);
    f32x4 acc[4][4];   // [ct][k]
    #pragma unroll
    for (int ct = 0; ct < 4; ++ct)
        #pragma unroll
        for (int k = 0; k < 4; ++k)
            acc[ct][k] = (f32x4){0.f, 0.f, 0.f, 0.f};

    #pragma unroll
    for (int kk = 0; kk < 4; ++kk) {
        int d0 = kk * 32 + g8;
        bf16x8 hf = *(const bf16x8*)&h_lds[irow * HS + d0];
        float hff[8];
        #pragma unroll
        for (int e = 0; e < 8; ++e) hff[e] = (float)hf[e];
        bf16x8 hk[4];
        #pragma unroll
        for (int k = 0; k < 4; ++k) {
            float4 alo = *(const float4*)&a_lds[k * ND + d0];
            float4 ahi = *(const float4*)&a_lds[k * ND + d0 + 4];
            bf16x8 r;
            r[0] = (__bf16)(hff[0] * alo.x); r[1] = (__bf16)(hff[1] * alo.y);
            r[2] = (__bf16)(hff[2] * alo.z); r[3] = (__bf16)(hff[3] * alo.w);
            r[4] = (__bf16)(hff[4] * ahi.x); r[5] = (__bf16)(hff[5] * ahi.y);
            r[6] = (__bf16)(hff[6] * ahi.z); r[7] = (__bf16)(hff[7] * ahi.w);
            hk[k] = r;
        }
        bf16x8 bfr[4];
        #pragma unroll
        for (int ct = 0; ct < 4; ++ct)
            bfr[ct] = *(const bf16x8*)&h_lds[(ct * 16 + (l & 15)) * HS + d0];
        #pragma unroll
        for (int ct = 0; ct < 4; ++ct)
            #pragma unroll
            for (int k = 0; k < 4; ++k)
                acc[ct][k] = __builtin_amdgcn_mfma_f32_16x16x32_bf16(hk[k], bfr[ct], acc[ct][k], 0, 0, 0);
    }

    // ---- fused leakyrelu + adj-select (in registers) ----
    float sel[4][4];   // [ct][r]
    #pragma unroll
    for (int ct = 0; ct < 4; ++ct)
        #pragma unroll
        for (int r = 0; r < 4; ++r) {
            float e0 = fmaxf(acc[ct][0][r], 0.2f * acc[ct][0][r]);
            float e1 = fmaxf(acc[ct][1][r], 0.2f * acc[ct][1][r]);
            float e2 = fmaxf(acc[ct][2][r], 0.2f * acc[ct][2][r]);
            float e3 = fmaxf(acc[ct][3][r], 0.2f * acc[ct][3][r]);
            int av = adjv[ct][r];
            sel[ct][r] = av == 1 ? e0 : av == 2 ? e1 : av == 3 ? e2 : av == 4 ? e3 : -9.0e15f;
        }

    // ---- in-register softmax: row i0+r lives in this 16-lane group ----
    float inv[4];
    #pragma unroll
    for (int r = 0; r < 4; ++r) {
        float m = fmaxf(fmaxf(sel[0][r], sel[1][r]), fmaxf(sel[2][r], sel[3][r]));
        m = fmaxf(m, __shfl_xor(m, 1));
        m = fmaxf(m, __shfl_xor(m, 2));
        m = fmaxf(m, __shfl_xor(m, 4));
        m = fmaxf(m, __shfl_xor(m, 8));
        float p0 = __expf(sel[0][r] - m);
        float p1 = __expf(sel[1][r] - m);
        float p2 = __expf(sel[2][r] - m);
        float p3 = __expf(sel[3][r] - m);
        float s = p0 + p1 + p2 + p3;
        s += __shfl_xor(s, 1);
        s += __shfl_xor(s, 2);
        s += __shfl_xor(s, 4);
        s += __shfl_xor(s, 8);
        inv[r] = 1.0f / s;
        int i = i0 + r;
        al_lds[i * AS +  0 + (l & 15)] = (__bf16)p0;   // unnormalized; scaled at PV store
        al_lds[i * AS + 16 + (l & 15)] = (__bf16)p1;
        al_lds[i * AS + 32 + (l & 15)] = (__bf16)p2;
        al_lds[i * AS + 48 + (l & 15)] = (__bf16)p3;
    }

    // ---- PV: out = diag(inv) * (P @ h); B-frags via hardware transpose read ----
    const int ia = w * 16 + (l & 15);
    bf16x8 aA0 = *(const bf16x8*)&al_lds[ia * AS + g8];
    bf16x8 aA1 = *(const bf16x8*)&al_lds[ia * AS + 32 + g8];
    float* outb = out + (size_t)b * NN * ND;
    // tr-read per-lane address: group window = 128B at (dt*2048 + g*256); lane slot = (l&15)*8
    unsigned trb = (unsigned)(unsigned long long)(&h_tr[0])
                 + (unsigned)(((l & 15) << 3) + (g << 8));
    #pragma unroll
    for (int dt = 0; dt < 8; ++dt) {
        unsigned ab = trb + dt * 2048;
        bf16x4 r0, r1, r2, r3;
        asm volatile("ds_read_b64_tr_b16 %0, %1"             : "=v"(r0) : "v"(ab));
        asm volatile("ds_read_b64_tr_b16 %0, %1 offset:128"  : "=v"(r1) : "v"(ab));
        asm volatile("ds_read_b64_tr_b16 %0, %1 offset:1024" : "=v"(r2) : "v"(ab));
        asm volatile("ds_read_b64_tr_b16 %0, %1 offset:1152" : "=v"(r3) : "v"(ab));
        asm volatile("s_waitcnt lgkmcnt(0)" ::: "memory");
        __builtin_amdgcn_sched_barrier(0);
        bf16x8 B0 = __builtin_shufflevector(r0, r1, 0, 1, 2, 3, 4, 5, 6, 7);
        bf16x8 B1 = __builtin_shufflevector(r2, r3, 0, 1, 2, 3, 4, 5, 6, 7);
        f32x4 o = {0.f, 0.f, 0.f, 0.f};
        o = __builtin_amdgcn_mfma_f32_16x16x32_bf16(aA0, B0, o, 0, 0, 0);
        o = __builtin_amdgcn_mfma_f32_16x16x32_bf16(aA1, B1, o, 0, 0, 0);
        int dr = dt * 16 + (l & 15);
        #pragma unroll
        for (int r = 0; r < 4; ++r)
            outb[(i0 + r) * ND + dr] = o[r] * inv[r];
    }
}

extern "C" void kernel_launch(void* const* d_in, const int* in_sizes, int n_in,
                              void* d_out, int out_size, void* d_ws, size_t ws_size,
                              hipStream_t stream) {
    const float* hidden = (const float*)d_in[0];
    const int*   adj    = (const int*)d_in[1];
    const float* a      = (const float*)d_in[2];
    float*       out    = (float*)d_out;
    gat_kernel<<<NB, 256, 0, stream>>>(hidden, adj, a, out);
}